// Round 10
// baseline (130.653 us; speedup 1.0000x reference)
//
#include <hip/hip_runtime.h>
#include <hip/hip_fp16.h>

#define PTAB_STRIDE 64   // halves per row = 128 B

typedef float    f32x4 __attribute__((ext_vector_type(4)));
typedef _Float16 half8 __attribute__((ext_vector_type(8)));
typedef _Float16 h2    __attribute__((ext_vector_type(2)));

__device__ __forceinline__ h2 u2h2(unsigned int u) {
    union { unsigned int u; h2 h; } c; c.u = u; return c.h;
}

__device__ __forceinline__ float fdot2x(h2 a, h2 b, float c) {
#if __has_builtin(__builtin_amdgcn_fdot2)
    return __builtin_amdgcn_fdot2(a, b, c, false);
#else
    return c + (float)a[0] * (float)b[0] + (float)a[1] * (float)b[1];
#endif
}

#if __has_builtin(__builtin_amdgcn_permlane16_swap)
#define HAVE_PL16 1
#else
#define HAVE_PL16 0
#endif
#if __has_builtin(__builtin_amdgcn_permlane32_swap)
#define HAVE_PL32 1
#else
#define HAVE_PL32 0
#endif

// DPP permute (VALU pipe). ctrl: 0xB1=quad xor1, 0x4E=quad xor2,
// 0x141=row_half_mirror (xor7), 0x140=row_mirror (xor15).
#define DPPX(v, ctrl) \
    ((unsigned)__builtin_amdgcn_update_dpp(0, (int)(v), (ctrl), 0xf, 0xf, true))

// xor16 exchange: A = (lane&16 ? foreign : own), B = complementary (native);
// fallback: A = own, B = foreign for all lanes.
__device__ __forceinline__ void xsw16(unsigned p, unsigned &A, unsigned &B) {
#if HAVE_PL16
    auto rr = __builtin_amdgcn_permlane16_swap(p, p, false, false);
    A = (unsigned)rr[0]; B = (unsigned)rr[1];
#else
    A = p;
    B = (unsigned)__builtin_amdgcn_ds_swizzle((int)p, 0x401F);  // xor16
#endif
}

// xor32 exchange: P = (lane&32 ? foreign : own), Q = complementary (native);
// fallback: P = own, Q = foreign.
__device__ __forceinline__ void xsw32(unsigned x, unsigned &P, unsigned &Q) {
#if HAVE_PL32
    auto rr = __builtin_amdgcn_permlane32_swap(x, x, false, false);
    P = (unsigned)rr[0]; Q = (unsigned)rr[1];
#else
    P = x;
    Q = (unsigned)__builtin_amdgcn_ds_bpermute(
            (int)(((threadIdx.x ^ 32) & 63) << 2), (int)x);
#endif
}

// ---------------------------------------------------------------------------
// Kernel 0: pack B-fragments (W^T, fp16, zero-padded to K=320 x N=64) in the
// exact mfma_f32_16x16x32_f16 per-lane layout, + fused bias table.
// ---------------------------------------------------------------------------
__global__ __launch_bounds__(64) void prep_kernel(
    const float* __restrict__ Wih, const float* __restrict__ bih,
    const float* __restrict__ bhh, __half* __restrict__ Bfrag,
    float* __restrict__ bias64)
{
    const int lane = threadIdx.x;
    const int st   = blockIdx.x;
    if (st == 40) {
        if (lane < 64) bias64[lane] = (lane < 50) ? bih[lane] + bhh[lane] : 0.f;
        return;
    }
    const int s  = st >> 2, t = st & 3;
    const int n  = 16 * t + (lane & 15);
    const int kb = lane >> 4;
    half8 v;
    #pragma unroll
    for (int j = 0; j < 8; ++j) {
        const int k = 32 * s + 8 * kb + j;
        float w = 0.f;
        if (n < 50 && k < 300) w = Wih[n * 300 + k];
        v[j] = (_Float16)w;
    }
    *reinterpret_cast<half8*>(Bfrag + ((size_t)st * 64 + lane) * 8) = v;
}

// ---------------------------------------------------------------------------
// Phase 1: ptab[v][h] = fp16( dot(emb[v,:], W_ih[h,:]) + b_ih + b_hh )
// One wave per 16 vocab rows, 4 N-tile accumulators, 40 MFMAs. (unchanged)
// ---------------------------------------------------------------------------
__global__ __launch_bounds__(64) void ptab_mfma(
    const float* __restrict__ emb, const __half* __restrict__ Bfrag,
    const float* __restrict__ bias64, __half* __restrict__ ptab)
{
    const int lane = threadIdx.x;
    const int v0   = blockIdx.x * 16;
    const int m    = lane & 15;
    const int kb   = lane >> 4;
    const float* Erow = emb + (size_t)(v0 + m) * 300;
    const half8* BF   = reinterpret_cast<const half8*>(Bfrag);

    f32x4 acc[4];
    #pragma unroll
    for (int t = 0; t < 4; ++t) acc[t] = (f32x4){0.f, 0.f, 0.f, 0.f};

    #pragma unroll
    for (int s = 0; s < 9; ++s) {
        const int k0 = 32 * s + 8 * kb;
        float4 p0 = *(const float4*)(Erow + k0);
        float4 p1 = *(const float4*)(Erow + k0 + 4);
        half8 a;
        a[0] = (_Float16)p0.x; a[1] = (_Float16)p0.y;
        a[2] = (_Float16)p0.z; a[3] = (_Float16)p0.w;
        a[4] = (_Float16)p1.x; a[5] = (_Float16)p1.y;
        a[6] = (_Float16)p1.z; a[7] = (_Float16)p1.w;
        #pragma unroll
        for (int t = 0; t < 4; ++t)
            acc[t] = __builtin_amdgcn_mfma_f32_16x16x32_f16(
                a, BF[(4 * s + t) * 64 + lane], acc[t], 0, 0, 0);
    }
    {   // tail K-step s=9: k = 288..319, valid only k < 300
        half8 a;
        #pragma unroll
        for (int j = 0; j < 8; ++j) {
            const int k = 288 + 8 * kb + j;
            float e = 0.f;
            if (k < 300) e = Erow[k];
            a[j] = (_Float16)e;
        }
        #pragma unroll
        for (int t = 0; t < 4; ++t)
            acc[t] = __builtin_amdgcn_mfma_f32_16x16x32_f16(
                a, BF[(36 + t) * 64 + lane], acc[t], 0, 0, 0);
    }

    const int nn = lane & 15;
    #pragma unroll
    for (int t = 0; t < 4; ++t) {
        const float bt = bias64[16 * t + nn];
        #pragma unroll
        for (int r = 0; r < 4; ++r)
            ptab[(size_t)(v0 + 4 * kb + r) * PTAB_STRIDE + 16 * t + nn] =
                (__half)(acc[t][r] + bt);
    }
}

// ---------------------------------------------------------------------------
// Phase 2: recurrence + head. One sequence per wave, 256 waves.
// h-broadcast is now a VALU-ONLY xor all-gather (no DS in the loop):
//   pack(xor1 via quad_perm 0xB1) -> permlane16_swap (xor16) ->
//   permlane32_swap (xor32) -> quad_perm 0x4E (xor2) -> half_mirror (xor7)
//   -> mirror (xor15).  Masks {1,2,7,15,16,32} span F2^6, so lane l's 32
//   dwords hold h[l ^ delta ^ e ^ m(F)] for delta in {0,2,7,5,15,13,8,10},
//   e = half, m(F) per swap family {P,Q,R,S}. Each lane pre-loads its W_hh
//   row in EXACTLY that order (per-lane xor index arithmetic), so the dot
//   is 32 v_dot2_f32_f16 — order-invariant, no reordering needed.
// Lanes >=50: W=0 and x=0 -> h stays exactly 0, never pollutes others.
// W regs pinned via asm "+v" (r8 lesson: prevents remat/reload in-loop).
// ---------------------------------------------------------------------------
__global__ __launch_bounds__(64, 1) void rnn_kernel(
    const int* __restrict__ tokens, const __half* __restrict__ ptab,
    const float* __restrict__ Whh,
    const float* __restrict__ Wfc, const float* __restrict__ bfc,
    float* __restrict__ out)
{
    __shared__ int stok[544];
    const int lane = threadIdx.x;
    const int b    = blockIdx.x;

    #pragma unroll
    for (int k = 0; k < 8; ++k)
        stok[lane + 64 * k] = tokens[b * 512 + lane + 64 * k];
    if (lane < 32) stok[512 + lane] = 0;     // pad: token 0 -> valid row
    __syncthreads();

    // per-lane slot->h-index masks (depend on which swap path compiled in)
    const int mA16 = HAVE_PL16 ? ((lane & 16) ? 16 : 0) : 0;
    const int mB16 = HAVE_PL16 ? ((lane & 16) ? 0 : 16) : 16;
    const int aP32 = HAVE_PL32 ? ((lane & 32) ? 32 : 0) : 0;
    const int aQ32 = HAVE_PL32 ? ((lane & 32) ? 0 : 32) : 32;
    const int mfam[4] = {mA16 | aP32, mA16 | aQ32, mB16 | aP32, mB16 | aQ32};
    const int dlt[8]  = {0, 2, 7, 5, 15, 13, 8, 10};

    // W_hh row of this lane, packed in gather order, pinned in VGPRs.
    unsigned wpk[8][4];
    #pragma unroll
    for (int di = 0; di < 8; ++di) {
        #pragma unroll
        for (int f = 0; f < 4; ++f) {
            const int ka = lane ^ dlt[di] ^ mfam[f];
            const int kb = ka ^ 1;
            _Float16 wa = (lane < 50 && ka < 50)
                              ? (_Float16)Whh[lane * 50 + ka] : (_Float16)0.f;
            _Float16 wb = (lane < 50 && kb < 50)
                              ? (_Float16)Whh[lane * 50 + kb] : (_Float16)0.f;
            union { h2 h; unsigned u; } c;
            c.h = (h2){wa, wb};
            wpk[di][f] = c.u;
        }
    }
    #pragma unroll
    for (int di = 0; di < 8; ++di)
        #pragma unroll
        for (int f = 0; f < 4; ++f)
            asm volatile("" : "+v"(wpk[di][f]));   // opaque: no remat/reload

    float h = 0.f;

#define GA(T) ptab[(size_t)(T) * PTAB_STRIDE + lane]

    __half x0 = GA(stok[0]), x1 = GA(stok[1]), x2 = GA(stok[2]), x3 = GA(stok[3]);
    __half x4 = GA(stok[4]), x5 = GA(stok[5]), x6 = GA(stok[6]), x7 = GA(stok[7]);
    int k0 = stok[8],  k1 = stok[9],  k2 = stok[10], k3 = stok[11];
    int k4 = stok[12], k5 = stok[13], k6 = stok[14], k7 = stok[15];

#define RNN_STEP(XV)                                                         \
    {                                                                        \
        union { _Float16 hf; unsigned short us; } hcv;                       \
        hcv.hf = (_Float16)h;                                                \
        unsigned hh = hcv.us;                                                \
        unsigned nb = DPPX(hh, 0xB1);            /* xor1 */                  \
        unsigned p  = hh | (nb << 16);                                       \
        unsigned A, B;                                                       \
        xsw16(p, A, B);                          /* xor16 */                 \
        unsigned g[8][4];                                                    \
        xsw32(A, g[0][0], g[0][1]);              /* xor32 */                 \
        xsw32(B, g[0][2], g[0][3]);                                          \
        _Pragma("unroll")                                                    \
        for (int f = 0; f < 4; ++f)                                          \
            g[1][f] = DPPX(g[0][f], 0x4E);       /* xor2 */                  \
        _Pragma("unroll")                                                    \
        for (int f = 0; f < 4; ++f) {                                        \
            g[2][f] = DPPX(g[0][f], 0x141);      /* xor7 */                  \
            g[3][f] = DPPX(g[1][f], 0x141);                                  \
        }                                                                    \
        _Pragma("unroll")                                                    \
        for (int f = 0; f < 4; ++f) {                                        \
            g[4][f] = DPPX(g[0][f], 0x140);      /* xor15 */                 \
            g[5][f] = DPPX(g[1][f], 0x140);                                  \
            g[6][f] = DPPX(g[2][f], 0x140);                                  \
            g[7][f] = DPPX(g[3][f], 0x140);                                  \
        }                                                                    \
        float s[4] = {0.f, 0.f, 0.f, 0.f};                                   \
        _Pragma("unroll")                                                    \
        for (int di = 0; di < 8; ++di) {                                     \
            _Pragma("unroll")                                                \
            for (int f = 0; f < 4; ++f)                                      \
                s[f] = fdot2x(u2h2(g[di][f]), u2h2(wpk[di][f]), s[f]);       \
        }                                                                    \
        float a = (float)(XV) + ((s[0] + s[1]) + (s[2] + s[3]));             \
        a = fminf(9.f, fmaxf(-9.f, a));                                      \
        float e = __expf(2.f * a);                                           \
        h = fmaf(-2.f, __builtin_amdgcn_rcpf(e + 1.f), 1.f);                 \
    }

    for (int t = 0; t < 512; t += 8) {
        __half n0 = GA(k0), n1 = GA(k1), n2 = GA(k2), n3 = GA(k3);
        __half n4 = GA(k4), n5 = GA(k5), n6 = GA(k6), n7 = GA(k7);
        k0 = stok[t + 16]; k1 = stok[t + 17]; k2 = stok[t + 18]; k3 = stok[t + 19];
        k4 = stok[t + 20]; k5 = stok[t + 21]; k6 = stok[t + 22]; k7 = stok[t + 23];

        RNN_STEP(x0); RNN_STEP(x1); RNN_STEP(x2); RNN_STEP(x3);
        RNN_STEP(x4); RNN_STEP(x5); RNN_STEP(x6); RNN_STEP(x7);

        x0 = n0; x1 = n1; x2 = n2; x3 = n3;
        x4 = n4; x5 = n5; x6 = n6; x7 = n7;
    }
#undef RNN_STEP
#undef GA

    // ---- head: out[b][o] = sum_h h[h] * W_fc[o][h] + b_fc[o] ----
    float hv = (lane < 50) ? h : 0.f;
    #pragma unroll
    for (int o = 0; o < 4; ++o) {
        float w = (lane < 50) ? Wfc[o * 50 + lane] : 0.f;
        float p = hv * w;
        #pragma unroll
        for (int s = 32; s > 0; s >>= 1) p += __shfl_xor(p, s, 64);
        if (lane == 0) out[b * 4 + o] = p + bfc[o];
    }
}

extern "C" void kernel_launch(void* const* d_in, const int* in_sizes, int n_in,
                              void* d_out, int out_size, void* d_ws, size_t ws_size,
                              hipStream_t stream)
{
    const int*   tokens = (const int*)d_in[0];
    const float* emb    = (const float*)d_in[1];
    const float* Wih    = (const float*)d_in[2];
    const float* Whh    = (const float*)d_in[3];
    const float* bih    = (const float*)d_in[4];
    const float* bhh    = (const float*)d_in[5];
    const float* Wfc    = (const float*)d_in[6];
    const float* bfc    = (const float*)d_in[7];

    char* ws = (char*)d_ws;
    __half* ptab   = (__half*)ws;                       // 6,400,000 B
    __half* Bfrag  = (__half*)(ws + 6400000);           //    40,960 B
    float*  bias64 = (float*)(ws + 6440960);            //       256 B
    float*  outp   = (float*)d_out;

    prep_kernel<<<41, 64, 0, stream>>>(Wih, bih, bhh, Bfrag, bias64);
    ptab_mfma<<<3125, 64, 0, stream>>>(emb, Bfrag, bias64, ptab);
    rnn_kernel<<<256, 64, 0, stream>>>(tokens, ptab, Whh, Wfc, bfc, outp);
}